// Round 2
// baseline (72.457 us; speedup 1.0000x reference)
//
#include <hip/hip_runtime.h>
#include <math.h>

#define Bdim 16
#define Cdim 512
#define Ldim 4096
#define Gdim 32
#define CPG  16
#define HALF 8
#define EPSV 1e-5f

#define THREADS 256
#define NWAVES  (THREADS / 64)
#define QSPLIT  4                 // L split into 4 slices of 1024
#define NBG     (Bdim * Gdim)     // 512
#define NBLK    (NBG * QSPLIT)    // 2048
#define LSLICE  (Ldim / QSPLIT)   // 1024

// ws layout: [NBG][QSPLIT][10] partials, then [NBG][10] finalized stats
#define WS_PART_STRIDE 10
#define WS_STATS_OFF   (NBG * QSPLIT * WS_PART_STRIDE)

__device__ __forceinline__ float wave_reduce_sum(float v) {
#pragma unroll
    for (int off = 32; off > 0; off >>= 1)
        v += __shfl_xor(v, off, 64);
    return v;
}

__device__ __forceinline__ float sigmoidf_(float x) {
    return 1.0f / (1.0f + expf(-x));
}

// ---------------- K1: partial stats per (b,g,q) ----------------
__global__ __launch_bounds__(THREADS, 8) void k1_stats(
    const float* __restrict__ x, float* __restrict__ ws)
{
    const int bid = blockIdx.x;
    const int bg  = bid >> 2;
    const int q   = bid & 3;
    const int b   = bg >> 5;
    const int g   = bg & 31;
    const int tid = threadIdx.x;
    const int wave = tid >> 6;
    const int lane = tid & 63;

    const float* xb = x + ((size_t)b * Cdim + (size_t)g * CPG) * Ldim
                        + q * LSLICE + tid * 4;

    float acc[10];
#pragma unroll
    for (int k = 0; k < 10; ++k) acc[k] = 0.f;

    // x1 channels 0..7: per-channel sums
#pragma unroll
    for (int c = 0; c < HALF; ++c) {
        const float4 v = *reinterpret_cast<const float4*>(xb + (size_t)c * Ldim);
        acc[c] = (v.x + v.y) + (v.z + v.w);
    }
    // x2 channels 8..15: sum + ssq
#pragma unroll
    for (int c = 0; c < HALF; ++c) {
        const float4 v = *reinterpret_cast<const float4*>(xb + (size_t)(HALF + c) * Ldim);
        acc[8] += (v.x + v.y) + (v.z + v.w);
        acc[9] += (v.x * v.x + v.y * v.y) + (v.z * v.z + v.w * v.w);
    }

    __shared__ float red[NWAVES][10];
#pragma unroll
    for (int k = 0; k < 10; ++k) {
        const float t = wave_reduce_sum(acc[k]);
        if (lane == 0) red[wave][k] = t;
    }
    __syncthreads();

    if (tid < 10) {
        float s = 0.f;
#pragma unroll
        for (int w = 0; w < NWAVES; ++w) s += red[w][tid];
        ws[(size_t)bid * WS_PART_STRIDE + tid] = s;
    }
}

// ---------------- K2: finalize per (b,g) constants ----------------
// out stats: w1[8], A2, B2  where  w2(l) = sigmoid(A2 * sum_c gw[c]*x2[c,l] + B2)
__global__ __launch_bounds__(THREADS) void k2_finalize(
    const float* __restrict__ ws_in, float* __restrict__ ws_out,
    const float* __restrict__ cw_w, const float* __restrict__ cw_b,
    const float* __restrict__ sw_w, const float* __restrict__ sw_b,
    const float* __restrict__ gn_w, const float* __restrict__ gn_b)
{
    const int bg = blockIdx.x * THREADS + threadIdx.x;
    if (bg >= NBG) return;
    const int g = bg & 31;

    float s[10];
#pragma unroll
    for (int k = 0; k < 10; ++k) {
        float t = 0.f;
#pragma unroll
        for (int q = 0; q < QSPLIT; ++q)
            t += ws_in[((size_t)bg * QSPLIT + q) * WS_PART_STRIDE + k];
        s[k] = t;
    }

    const float cww = cw_w[g], cwb = cw_b[g];
    float* o = ws_out + (size_t)bg * 10;
#pragma unroll
    for (int c = 0; c < HALF; ++c) {
        const float ca = s[c] * (1.0f / Ldim);
        o[c] = sigmoidf_(ca * cww + cwb);
    }

    const float inv_n = 1.0f / (HALF * Ldim);
    const float mu  = s[8] * inv_n;
    const float var = s[9] * inv_n - mu * mu;
    const float rs  = rsqrtf(var + EPSV);

    float sgw = 0.f, mgb = 0.f;
#pragma unroll
    for (int c = 0; c < HALF; ++c) {
        sgw += gn_w[g * HALF + c];
        mgb += gn_b[g * HALF + c];
    }
    mgb *= (1.0f / HALF);

    const float sww = sw_w[g], swb = sw_b[g];
    const float k0  = rs * (1.0f / HALF);
    o[8] = k0 * sww;                              // A2
    o[9] = (-mu * sgw * k0 + mgb) * sww + swb;    // B2
}

// ---------------- K3: apply (pure streaming, no reductions) ----------------
__global__ __launch_bounds__(THREADS, 8) void k3_apply(
    const float* __restrict__ x, const float* __restrict__ stats,
    const float* __restrict__ gn_w, float* __restrict__ out)
{
    const int bid = blockIdx.x;
    const int bg  = bid >> 2;
    const int q   = bid & 3;
    const int b   = bg >> 5;
    const int g   = bg & 31;
    const int tid = threadIdx.x;

    const size_t loff = (size_t)(q * LSLICE + tid * 4);
    const float* xb   = x + ((size_t)b * Cdim + (size_t)g * CPG) * Ldim + loff;
    float*       outb = out + (size_t)b * Cdim * Ldim + loff;

    const float* st = stats + (size_t)bg * 10;   // block-uniform -> scalar loads
    const float A2 = st[8], B2 = st[9];

    // x1: load all 8 (MLP), scale by w1[c], store
    float4 a[HALF];
#pragma unroll
    for (int c = 0; c < HALF; ++c)
        a[c] = *reinterpret_cast<const float4*>(xb + (size_t)c * Ldim);
#pragma unroll
    for (int c = 0; c < HALF; ++c) {
        const float w1 = st[c];
        float4 v = a[c];
        v.x *= w1; v.y *= w1; v.z *= w1; v.w *= w1;
        *reinterpret_cast<float4*>(outb + (size_t)(c * Gdim + g) * Ldim) = v;
    }

    // x2: load all 8, dot with gw -> w2(l), scale, store
    float4 bb[HALF];
#pragma unroll
    for (int c = 0; c < HALF; ++c)
        bb[c] = *reinterpret_cast<const float4*>(xb + (size_t)(HALF + c) * Ldim);

    float4 wsum; wsum.x = 0.f; wsum.y = 0.f; wsum.z = 0.f; wsum.w = 0.f;
#pragma unroll
    for (int c = 0; c < HALF; ++c) {
        const float gw = gn_w[g * HALF + c];
        wsum.x += gw * bb[c].x;
        wsum.y += gw * bb[c].y;
        wsum.z += gw * bb[c].z;
        wsum.w += gw * bb[c].w;
    }
    float4 w2;
    w2.x = sigmoidf_(A2 * wsum.x + B2);
    w2.y = sigmoidf_(A2 * wsum.y + B2);
    w2.z = sigmoidf_(A2 * wsum.z + B2);
    w2.w = sigmoidf_(A2 * wsum.w + B2);

#pragma unroll
    for (int c = 0; c < HALF; ++c) {
        float4 v = bb[c];
        v.x *= w2.x; v.y *= w2.y; v.z *= w2.z; v.w *= w2.w;
        *reinterpret_cast<float4*>(outb + (size_t)((HALF + c) * Gdim + g) * Ldim) = v;
    }
}

extern "C" void kernel_launch(void* const* d_in, const int* in_sizes, int n_in,
                              void* d_out, int out_size, void* d_ws, size_t ws_size,
                              hipStream_t stream) {
    const float* x    = (const float*)d_in[0];
    const float* cw_w = (const float*)d_in[1];
    const float* cw_b = (const float*)d_in[2];
    const float* sw_w = (const float*)d_in[3];
    const float* sw_b = (const float*)d_in[4];
    const float* gn_w = (const float*)d_in[5];
    const float* gn_b = (const float*)d_in[6];
    float* out = (float*)d_out;
    float* ws  = (float*)d_ws;

    float* ws_part  = ws;
    float* ws_stats = ws + WS_STATS_OFF;

    k1_stats<<<dim3(NBLK), dim3(THREADS), 0, stream>>>(x, ws_part);
    k2_finalize<<<dim3((NBG + THREADS - 1) / THREADS), dim3(THREADS), 0, stream>>>(
        ws_part, ws_stats, cw_w, cw_b, sw_w, sw_b, gn_w, gn_b);
    k3_apply<<<dim3(NBLK), dim3(THREADS), 0, stream>>>(x, ws_stats, gn_w, out);
}

// Round 3
// 65.692 us; speedup vs baseline: 1.1030x; 1.1030x over previous
//
#include <hip/hip_runtime.h>
#include <math.h>

#define Bdim 16
#define Cdim 512
#define Ldim 4096
#define Gdim 32
#define CPG  16
#define HALF 8
#define EPSV 1e-5f

#define THREADS 512
#define NWAVES  (THREADS / 64)   // 8 waves: one per channel of the half-group
#define NBG     (Bdim * Gdim)    // 512

__device__ __forceinline__ float wave_reduce_sum(float v) {
#pragma unroll
    for (int off = 32; off > 0; off >>= 1)
        v += __shfl_xor(v, off, 64);
    return v;
}

__device__ __forceinline__ float sigmoidf_(float x) {
    return 1.0f / (1.0f + expf(-x));
}

// 1024 blocks: bid < 512 -> x1 phase for bg=bid; bid >= 512 -> x2 phase.
// Phase A (x1): wave w owns channel w's full row. Wave-local mean -> no barriers.
// Phase B (x2): wave w owns channel 8+w for stats (1 barrier), then threads
//               remap across l for the channel-dot + gated write.
__global__ __launch_bounds__(THREADS, 8) void fused_ham_kernel(
    const float* __restrict__ x,
    const float* __restrict__ cw_w, const float* __restrict__ cw_b,
    const float* __restrict__ sw_w, const float* __restrict__ sw_b,
    const float* __restrict__ gn_w, const float* __restrict__ gn_b,
    float* __restrict__ out)
{
    const int bid  = blockIdx.x;
    const int ph   = bid >> 9;         // 0: x1, 1: x2
    const int bg   = bid & (NBG - 1);
    const int b    = bg >> 5;
    const int g    = bg & 31;
    const int tid  = threadIdx.x;
    const int wave = tid >> 6;
    const int lane = tid & 63;

    const float* xb   = x + ((size_t)b * Cdim + (size_t)g * CPG) * Ldim;
    float*       outb = out + (size_t)b * Cdim * Ldim;

    if (ph == 0) {
        // ---------- Phase A: x1 channels 0..7, one wave per channel ----------
        const float* row = xb + (size_t)wave * Ldim;
        float s = 0.f;
#pragma unroll
        for (int k = 0; k < 16; ++k) {
            const float4 v = *reinterpret_cast<const float4*>(row + k * 256 + lane * 4);
            s += (v.x + v.y) + (v.z + v.w);
        }
        s = wave_reduce_sum(s);
        const float ca = s * (1.0f / Ldim);
        const float w1 = sigmoidf_(ca * cw_w[g] + cw_b[g]);

        float* orow = outb + (size_t)(wave * Gdim + g) * Ldim;
#pragma unroll
        for (int k = 0; k < 16; ++k) {
            float4 v = *reinterpret_cast<const float4*>(row + k * 256 + lane * 4);
            v.x *= w1; v.y *= w1; v.z *= w1; v.w *= w1;
            *reinterpret_cast<float4*>(orow + k * 256 + lane * 4) = v;
        }
    } else {
        // ---------- Phase B: x2 channels 8..15 ----------
        const float* row = xb + (size_t)(HALF + wave) * Ldim;
        float sum = 0.f, ssq = 0.f;
#pragma unroll
        for (int k = 0; k < 16; ++k) {
            const float4 v = *reinterpret_cast<const float4*>(row + k * 256 + lane * 4);
            sum += (v.x + v.y) + (v.z + v.w);
            ssq += (v.x * v.x + v.y * v.y) + (v.z * v.z + v.w * v.w);
        }
        sum = wave_reduce_sum(sum);
        ssq = wave_reduce_sum(ssq);

        __shared__ float red[NWAVES][2];
        if (lane == 0) { red[wave][0] = sum; red[wave][1] = ssq; }
        __syncthreads();

        float tsum = 0.f, tssq = 0.f;
#pragma unroll
        for (int w = 0; w < NWAVES; ++w) { tsum += red[w][0]; tssq += red[w][1]; }
        const float inv_n = 1.0f / (HALF * Ldim);
        const float mu  = tsum * inv_n;
        const float var = tssq * inv_n - mu * mu;
        const float rs  = rsqrtf(var + EPSV);

        float gw[HALF];
        float sgw = 0.f, mgb = 0.f;
#pragma unroll
        for (int c = 0; c < HALF; ++c) {
            gw[c] = gn_w[g * HALF + c];
            sgw  += gw[c];
            mgb  += gn_b[g * HALF + c];
        }
        mgb *= (1.0f / HALF);
        const float k0 = rs * (1.0f / HALF);
        const float A2 = k0 * sw_w[g];
        const float B2 = (-mu * sgw * k0 + mgb) * sw_w[g] + sw_b[g];

        const float* xb2 = xb + (size_t)HALF * Ldim;
#pragma unroll
        for (int j = 0; j < 2; ++j) {
            const int l0 = tid * 4 + j * (Ldim / 2);
            float4 bb[HALF];
#pragma unroll
            for (int c = 0; c < HALF; ++c)
                bb[c] = *reinterpret_cast<const float4*>(xb2 + (size_t)c * Ldim + l0);

            float4 wsum; wsum.x = 0.f; wsum.y = 0.f; wsum.z = 0.f; wsum.w = 0.f;
#pragma unroll
            for (int c = 0; c < HALF; ++c) {
                wsum.x += gw[c] * bb[c].x;
                wsum.y += gw[c] * bb[c].y;
                wsum.z += gw[c] * bb[c].z;
                wsum.w += gw[c] * bb[c].w;
            }
            float4 w2;
            w2.x = sigmoidf_(A2 * wsum.x + B2);
            w2.y = sigmoidf_(A2 * wsum.y + B2);
            w2.z = sigmoidf_(A2 * wsum.z + B2);
            w2.w = sigmoidf_(A2 * wsum.w + B2);

#pragma unroll
            for (int c = 0; c < HALF; ++c) {
                float4 v = bb[c];
                v.x *= w2.x; v.y *= w2.y; v.z *= w2.z; v.w *= w2.w;
                *reinterpret_cast<float4*>(outb + (size_t)((HALF + c) * Gdim + g) * Ldim + l0) = v;
            }
        }
    }
}

extern "C" void kernel_launch(void* const* d_in, const int* in_sizes, int n_in,
                              void* d_out, int out_size, void* d_ws, size_t ws_size,
                              hipStream_t stream) {
    const float* x    = (const float*)d_in[0];
    const float* cw_w = (const float*)d_in[1];
    const float* cw_b = (const float*)d_in[2];
    const float* sw_w = (const float*)d_in[3];
    const float* sw_b = (const float*)d_in[4];
    const float* gn_w = (const float*)d_in[5];
    const float* gn_b = (const float*)d_in[6];
    float* out = (float*)d_out;

    fused_ham_kernel<<<dim3(2 * NBG), dim3(THREADS), 0, stream>>>(
        x, cw_w, cw_b, sw_w, sw_b, gn_w, gn_b, out);
}

// Round 5
// 64.726 us; speedup vs baseline: 1.1194x; 1.0149x over previous
//
#include <hip/hip_runtime.h>
#include <math.h>

#define Bdim 16
#define Cdim 512
#define Ldim 4096
#define Gdim 32
#define CPG  16
#define HALF 8
#define EPSV 1e-5f

#define THREADS 512
#define NWAVES  (THREADS / 64)   // 8 waves: one per channel of the half-group
#define NBG     (Bdim * Gdim)    // 512

typedef float fvec4 __attribute__((ext_vector_type(4)));

__device__ __forceinline__ float wave_reduce_sum(float v) {
#pragma unroll
    for (int off = 32; off > 0; off >>= 1)
        v += __shfl_xor(v, off, 64);
    return v;
}

__device__ __forceinline__ float sigmoidf_(float x) {
    return 1.0f / (1.0f + expf(-x));
}

__device__ __forceinline__ void nt_store4(float* p, float4 v) {
    fvec4 t;
    t.x = v.x; t.y = v.y; t.z = v.z; t.w = v.w;
    __builtin_nontemporal_store(t, reinterpret_cast<fvec4*>(p));
}

// 1024 blocks: bid < 512 -> x1 phase for bg=bid; bid >= 512 -> x2 phase.
// Phase A (x1): wave w owns channel w's full row. Wave-local mean -> no barriers.
// Phase B (x2): wave w owns channel 8+w for stats (1 barrier), then threads
//               remap across l for the channel-dot + gated write.
// All output stores are non-temporal so `out` never evicts x from L3:
// x (128 MB) stays L3-resident across graph replays -> HBM fetch collapses.
__global__ __launch_bounds__(THREADS, 8) void fused_ham_kernel(
    const float* __restrict__ x,
    const float* __restrict__ cw_w, const float* __restrict__ cw_b,
    const float* __restrict__ sw_w, const float* __restrict__ sw_b,
    const float* __restrict__ gn_w, const float* __restrict__ gn_b,
    float* __restrict__ out)
{
    const int bid  = blockIdx.x;
    const int ph   = bid >> 9;         // 0: x1, 1: x2
    const int bg   = bid & (NBG - 1);
    const int b    = bg >> 5;
    const int g    = bg & 31;
    const int tid  = threadIdx.x;
    const int wave = tid >> 6;
    const int lane = tid & 63;

    const float* xb   = x + ((size_t)b * Cdim + (size_t)g * CPG) * Ldim;
    float*       outb = out + (size_t)b * Cdim * Ldim;

    if (ph == 0) {
        // ---------- Phase A: x1 channels 0..7, one wave per channel ----------
        const float* row = xb + (size_t)wave * Ldim;
        float s = 0.f;
#pragma unroll
        for (int k = 0; k < 16; ++k) {
            const float4 v = *reinterpret_cast<const float4*>(row + k * 256 + lane * 4);
            s += (v.x + v.y) + (v.z + v.w);
        }
        s = wave_reduce_sum(s);
        const float ca = s * (1.0f / Ldim);
        const float w1 = sigmoidf_(ca * cw_w[g] + cw_b[g]);

        float* orow = outb + (size_t)(wave * Gdim + g) * Ldim;
#pragma unroll
        for (int k = 0; k < 16; ++k) {
            float4 v = *reinterpret_cast<const float4*>(row + k * 256 + lane * 4);
            v.x *= w1; v.y *= w1; v.z *= w1; v.w *= w1;
            nt_store4(orow + k * 256 + lane * 4, v);
        }
    } else {
        // ---------- Phase B: x2 channels 8..15 ----------
        const float* row = xb + (size_t)(HALF + wave) * Ldim;
        float sum = 0.f, ssq = 0.f;
#pragma unroll
        for (int k = 0; k < 16; ++k) {
            const float4 v = *reinterpret_cast<const float4*>(row + k * 256 + lane * 4);
            sum += (v.x + v.y) + (v.z + v.w);
            ssq += (v.x * v.x + v.y * v.y) + (v.z * v.z + v.w * v.w);
        }
        sum = wave_reduce_sum(sum);
        ssq = wave_reduce_sum(ssq);

        __shared__ float red[NWAVES][2];
        if (lane == 0) { red[wave][0] = sum; red[wave][1] = ssq; }
        __syncthreads();

        float tsum = 0.f, tssq = 0.f;
#pragma unroll
        for (int w = 0; w < NWAVES; ++w) { tsum += red[w][0]; tssq += red[w][1]; }
        const float inv_n = 1.0f / (HALF * Ldim);
        const float mu  = tsum * inv_n;
        const float var = tssq * inv_n - mu * mu;
        const float rs  = rsqrtf(var + EPSV);

        float gw[HALF];
        float sgw = 0.f, mgb = 0.f;
#pragma unroll
        for (int c = 0; c < HALF; ++c) {
            gw[c] = gn_w[g * HALF + c];
            sgw  += gw[c];
            mgb  += gn_b[g * HALF + c];
        }
        mgb *= (1.0f / HALF);
        const float k0 = rs * (1.0f / HALF);
        const float A2 = k0 * sw_w[g];
        const float B2 = (-mu * sgw * k0 + mgb) * sw_w[g] + sw_b[g];

        const float* xb2 = xb + (size_t)HALF * Ldim;
#pragma unroll
        for (int j = 0; j < 2; ++j) {
            const int l0 = tid * 4 + j * (Ldim / 2);
            float4 bb[HALF];
#pragma unroll
            for (int c = 0; c < HALF; ++c)
                bb[c] = *reinterpret_cast<const float4*>(xb2 + (size_t)c * Ldim + l0);

            float4 wsum; wsum.x = 0.f; wsum.y = 0.f; wsum.z = 0.f; wsum.w = 0.f;
#pragma unroll
            for (int c = 0; c < HALF; ++c) {
                wsum.x += gw[c] * bb[c].x;
                wsum.y += gw[c] * bb[c].y;
                wsum.z += gw[c] * bb[c].z;
                wsum.w += gw[c] * bb[c].w;
            }
            float4 w2;
            w2.x = sigmoidf_(A2 * wsum.x + B2);
            w2.y = sigmoidf_(A2 * wsum.y + B2);
            w2.z = sigmoidf_(A2 * wsum.z + B2);
            w2.w = sigmoidf_(A2 * wsum.w + B2);

#pragma unroll
            for (int c = 0; c < HALF; ++c) {
                float4 v = bb[c];
                v.x *= w2.x; v.y *= w2.y; v.z *= w2.z; v.w *= w2.w;
                nt_store4(outb + (size_t)((HALF + c) * Gdim + g) * Ldim + l0, v);
            }
        }
    }
}

extern "C" void kernel_launch(void* const* d_in, const int* in_sizes, int n_in,
                              void* d_out, int out_size, void* d_ws, size_t ws_size,
                              hipStream_t stream) {
    const float* x    = (const float*)d_in[0];
    const float* cw_w = (const float*)d_in[1];
    const float* cw_b = (const float*)d_in[2];
    const float* sw_w = (const float*)d_in[3];
    const float* sw_b = (const float*)d_in[4];
    const float* gn_w = (const float*)d_in[5];
    const float* gn_b = (const float*)d_in[6];
    float* out = (float*)d_out;

    fused_ham_kernel<<<dim3(2 * NBG), dim3(THREADS), 0, stream>>>(
        x, cw_w, cw_b, sw_w, sw_b, gn_w, gn_b, out);
}

// Round 6
// 44.786 us; speedup vs baseline: 1.6178x; 1.4452x over previous
//
#include <hip/hip_runtime.h>
#include <math.h>

#define Bdim 16
#define Cdim 512
#define Ldim 4096
#define Gdim 32
#define CPG  16
#define HALF 8
#define EPSV 1e-5f

#define THREADS 512
#define NWAVES  (THREADS / 64)
#define NBG     (Bdim * Gdim)    // 512

typedef float fvec4 __attribute__((ext_vector_type(4)));

__device__ __forceinline__ float wave_reduce_sum(float v) {
#pragma unroll
    for (int off = 32; off > 0; off >>= 1)
        v += __shfl_xor(v, off, 64);
    return v;
}

__device__ __forceinline__ float sigmoidf_(float x) {
    return 1.0f / (1.0f + expf(-x));
}

__device__ __forceinline__ fvec4 sigmoid4(fvec4 x) {
    fvec4 r;
    r.x = sigmoidf_(x.x); r.y = sigmoidf_(x.y);
    r.z = sigmoidf_(x.z); r.w = sigmoidf_(x.w);
    return r;
}

// liveness pin: forces v to stay materialized in VGPRs (compiler otherwise
// re-loads tiles from global after barriers — seen in R1, VGPR=56)
__device__ __forceinline__ void pin(fvec4& v) {
    asm volatile("" : "+v"(v));
}

__device__ __forceinline__ void nt_store(float* p, fvec4 v) {
    __builtin_nontemporal_store(v, reinterpret_cast<fvec4*>(p));
}

// 1024 blocks, interleaved phases: ph = bid&1, bg = bid>>1.
// Phase A (x1, ch 0..7): wave w owns channel w's entire row IN REGISTERS
//   (16 x fvec4 = 64 VGPR). Wave-shuffle mean -> w1 -> scale regs -> store.
//   No LDS, no barrier, x read exactly once.
// Phase B (x2, ch 8..15): thread owns columns {tid*4+j*2048} of all 8 rows
//   (16 x fvec4 = 64 VGPR). Partial sum/ssq -> one barrier (LDS combine) ->
//   A2/B2 -> per-l dot+sigmoid from regs -> store. x read exactly once;
//   tile pinned across the barrier.
__global__ __launch_bounds__(THREADS, 4) void fused_ham_kernel(
    const float* __restrict__ x,
    const float* __restrict__ cw_w, const float* __restrict__ cw_b,
    const float* __restrict__ sw_w, const float* __restrict__ sw_b,
    const float* __restrict__ gn_w, const float* __restrict__ gn_b,
    float* __restrict__ out)
{
    const int bid  = blockIdx.x;
    const int ph   = bid & 1;
    const int bg   = bid >> 1;
    const int b    = bg >> 5;
    const int g    = bg & 31;
    const int tid  = threadIdx.x;
    const int wave = tid >> 6;
    const int lane = tid & 63;

    const float* xb   = x + ((size_t)b * Cdim + (size_t)g * CPG) * Ldim;
    float*       outb = out + (size_t)b * Cdim * Ldim;

    if (ph == 0) {
        // ---------- Phase A ----------
        const float* row = xb + (size_t)wave * Ldim;
        fvec4 r[16];
#pragma unroll
        for (int k = 0; k < 16; ++k)
            r[k] = *reinterpret_cast<const fvec4*>(row + k * 256 + lane * 4);

        float s = 0.f;
#pragma unroll
        for (int k = 0; k < 16; ++k)
            s += (r[k].x + r[k].y) + (r[k].z + r[k].w);
#pragma unroll
        for (int k = 0; k < 16; ++k) pin(r[k]);

        s = wave_reduce_sum(s);
        const float w1 = sigmoidf_(s * (1.0f / Ldim) * cw_w[g] + cw_b[g]);

        float* orow = outb + (size_t)(wave * Gdim + g) * Ldim;
#pragma unroll
        for (int k = 0; k < 16; ++k)
            nt_store(orow + k * 256 + lane * 4, r[k] * w1);
    } else {
        // ---------- Phase B ----------
        const float* xb2 = xb + (size_t)HALF * Ldim;
        fvec4 bb[16];                      // [c][j] -> bb[c*2+j]
        float sum = 0.f, ssq = 0.f;
#pragma unroll
        for (int c = 0; c < HALF; ++c) {
#pragma unroll
            for (int j = 0; j < 2; ++j) {
                const fvec4 v = *reinterpret_cast<const fvec4*>(
                    xb2 + (size_t)c * Ldim + j * (Ldim / 2) + tid * 4);
                bb[c * 2 + j] = v;
                sum += (v.x + v.y) + (v.z + v.w);
                ssq += (v.x * v.x + v.y * v.y) + (v.z * v.z + v.w * v.w);
            }
        }
#pragma unroll
        for (int k = 0; k < 16; ++k) pin(bb[k]);

        sum = wave_reduce_sum(sum);
        ssq = wave_reduce_sum(ssq);

        __shared__ float red[NWAVES][2];
        if (lane == 0) { red[wave][0] = sum; red[wave][1] = ssq; }
        __syncthreads();

        float tsum = 0.f, tssq = 0.f;
#pragma unroll
        for (int w = 0; w < NWAVES; ++w) { tsum += red[w][0]; tssq += red[w][1]; }
        const float inv_n = 1.0f / (HALF * Ldim);
        const float mu  = tsum * inv_n;
        const float var = tssq * inv_n - mu * mu;
        const float rs  = rsqrtf(var + EPSV);

        float gw[HALF];
        float sgw = 0.f, mgb = 0.f;
#pragma unroll
        for (int c = 0; c < HALF; ++c) {
            gw[c] = gn_w[g * HALF + c];
            sgw  += gw[c];
            mgb  += gn_b[g * HALF + c];
        }
        mgb *= (1.0f / HALF);
        const float k0 = rs * (1.0f / HALF);
        const float A2 = k0 * sw_w[g];
        const float B2 = (-mu * sgw * k0 + mgb) * sw_w[g] + sw_b[g];

#pragma unroll
        for (int j = 0; j < 2; ++j) {
            fvec4 ws = 0.f;
#pragma unroll
            for (int c = 0; c < HALF; ++c)
                ws += gw[c] * bb[c * 2 + j];
            const fvec4 w2 = sigmoid4(A2 * ws + B2);

#pragma unroll
            for (int c = 0; c < HALF; ++c)
                nt_store(outb + (size_t)((HALF + c) * Gdim + g) * Ldim
                              + j * (Ldim / 2) + tid * 4,
                         bb[c * 2 + j] * w2);
        }
    }
}

extern "C" void kernel_launch(void* const* d_in, const int* in_sizes, int n_in,
                              void* d_out, int out_size, void* d_ws, size_t ws_size,
                              hipStream_t stream) {
    const float* x    = (const float*)d_in[0];
    const float* cw_w = (const float*)d_in[1];
    const float* cw_b = (const float*)d_in[2];
    const float* sw_w = (const float*)d_in[3];
    const float* sw_b = (const float*)d_in[4];
    const float* gn_w = (const float*)d_in[5];
    const float* gn_b = (const float*)d_in[6];
    float* out = (float*)d_out;

    fused_ham_kernel<<<dim3(2 * NBG), dim3(THREADS), 0, stream>>>(
        x, cw_w, cw_b, sw_w, sw_b, gn_w, gn_b, out);
}